// Round 1
// baseline (3268.191 us; speedup 1.0000x reference)
//
#include <hip/hip_runtime.h>
#include <cstdint>
#include <cstddef>

// dims
#define G_    16
#define A_    64
#define P_    32
#define DIN_  768
#define DEMB_ 384
#define HP_   256
#define HA_   128
#define GA_   1024      // G_*A_  (post-LSTM batch)
#define N1_   1024      // 4*HP_
#define K1_   1024      // DIN_+HP_ (fused A width)
#define N2_   512       // 4*HA_

// ---- workspace layout (float offsets) ----
// Bmat  [K1_][N1_]   rows 0..767 = w_embed@k_post, rows 768..1023 = r_post
// biasZ [N1_]
// gates [GA_][N1_]
// h     [GA_][HP_]
// c     [GA_][HP_]
// z_auth[A_][G_][N2_]
#define OFF_BMAT   0
#define OFF_BIASZ  (OFF_BMAT  + K1_*N1_)          // 1048576
#define OFF_GATES  (OFF_BIASZ + N1_)              // 1049600
#define OFF_H      (OFF_GATES + GA_*N1_)          // 2098176
#define OFF_C      (OFF_H     + GA_*HP_)          // 2360320
#define OFF_ZAUTH  (OFF_C     + GA_*HP_)          // 2622464
#define WS_FLOATS  (OFF_ZAUTH + A_*G_*N2_)        // 3146752 floats ~ 12.6 MB

__device__ __forceinline__ float sigmoidf_(float x) { return 1.0f / (1.0f + __expf(-x)); }

// ---------------- prep kernels ----------------

// Bmat rows 0..767 : WK[k][j] = sum_d w_embed[k][d] * k_post[d][j]
// grid (4, 192), block 256. block.y covers 4 k-rows.
__global__ __launch_bounds__(256) void k_wk(const float* __restrict__ w_embed,
                                            const float* __restrict__ k_post,
                                            float* __restrict__ Bmat) {
    int j  = blockIdx.x * 256 + threadIdx.x;
    int k0 = blockIdx.y * 4;
    float acc0 = 0.f, acc1 = 0.f, acc2 = 0.f, acc3 = 0.f;
    for (int d = 0; d < DEMB_; ++d) {
        float kp = k_post[(size_t)d * N1_ + j];
        acc0 += w_embed[(size_t)(k0 + 0) * DEMB_ + d] * kp;
        acc1 += w_embed[(size_t)(k0 + 1) * DEMB_ + d] * kp;
        acc2 += w_embed[(size_t)(k0 + 2) * DEMB_ + d] * kp;
        acc3 += w_embed[(size_t)(k0 + 3) * DEMB_ + d] * kp;
    }
    Bmat[(size_t)(k0 + 0) * N1_ + j] = acc0;
    Bmat[(size_t)(k0 + 1) * N1_ + j] = acc1;
    Bmat[(size_t)(k0 + 2) * N1_ + j] = acc2;
    Bmat[(size_t)(k0 + 3) * N1_ + j] = acc3;
}

// Bmat rows 768..1023 <- r_post  (256x1024 f32 = 65536 float4), grid 256 block 256
__global__ void k_copy_r(const float* __restrict__ r_post, float* __restrict__ Bmat) {
    int i = blockIdx.x * 256 + threadIdx.x;   // 0..65535
    const float4* src = (const float4*)r_post;
    float4* dst = (float4*)(Bmat + (size_t)DIN_ * N1_);
    dst[i] = src[i];
}

// biasZ[j] = sum_d b_embed[d]*k_post[d][j] + b_post[j]; grid 4, block 256
__global__ void k_bias(const float* __restrict__ b_embed, const float* __restrict__ k_post,
                       const float* __restrict__ b_post, float* __restrict__ biasZ) {
    int j = blockIdx.x * 256 + threadIdx.x;
    float acc = b_post[j];
    for (int d = 0; d < DEMB_; ++d)
        acc += b_embed[d] * k_post[(size_t)d * N1_ + j];
    biasZ[j] = acc;
}

// ---------------- post-LSTM step GEMM ----------------
// gates[b][j] = biasZ[j] + sum_{k<768} x[b*32+t][k]*Bmat[k][j] + sum_{k<256} h[b][k]*Bmat[768+k][j]
// 64x64 tile, BK=16, 512 threads (8 waves), micro 2x4 per thread.
#define BM 64
#define BN 64
#define BK 16
__global__ __launch_bounds__(512) void k_step(const float* __restrict__ x,
                                              const float* __restrict__ Bmat,
                                              const float* __restrict__ biasZ,
                                              const float* __restrict__ h,
                                              float* __restrict__ gates, int t) {
    __shared__ float As[BK][BM];   // transposed A tile
    __shared__ float Bs[BK][BN];
    const int tid = threadIdx.x;
    const int bm = blockIdx.y * BM;   // batch rows
    const int bn = blockIdx.x * BN;   // gate cols
    const int tx = tid & 15;          // col group: 4 cols
    const int ty = tid >> 4;          // row group: 2 rows (0..31)

    float acc[2][4] = {};

    // per-thread staging roles
    const int am = (tid & 255) >> 2;        // 0..63 (only tid<256 uses)
    const int akq = ((tid & 255) & 3) * 4;  // 0,4,8,12
    const int bkk = (tid - 256) >> 4;       // 0..15 (only tid>=256 uses)
    const int bnq = ((tid - 256) & 15) * 4;

    for (int kt = 0; kt < K1_ / BK; ++kt) {
        const int k0 = kt * BK;
        if (tid < 256) {
            const int row = bm + am;
            const int k = k0 + akq;
            float4 v;
            if (k < DIN_) {
                v = *(const float4*)&x[((size_t)row * P_ + t) * DIN_ + k];
            } else {
                v = *(const float4*)&h[(size_t)row * HP_ + (k - DIN_)];
            }
            As[akq + 0][am] = v.x;
            As[akq + 1][am] = v.y;
            As[akq + 2][am] = v.z;
            As[akq + 3][am] = v.w;
        } else {
            *(float4*)&Bs[bkk][bnq] =
                *(const float4*)&Bmat[(size_t)(k0 + bkk) * N1_ + bn + bnq];
        }
        __syncthreads();
#pragma unroll
        for (int kk = 0; kk < BK; ++kk) {
            const float2 a = *(const float2*)&As[kk][ty * 2];
            const float4 b = *(const float4*)&Bs[kk][tx * 4];
            acc[0][0] += a.x * b.x; acc[0][1] += a.x * b.y;
            acc[0][2] += a.x * b.z; acc[0][3] += a.x * b.w;
            acc[1][0] += a.y * b.x; acc[1][1] += a.y * b.y;
            acc[1][2] += a.y * b.z; acc[1][3] += a.y * b.w;
        }
        __syncthreads();
    }

    const float4 bz = *(const float4*)&biasZ[bn + tx * 4];
#pragma unroll
    for (int r = 0; r < 2; ++r) {
        float4 o;
        o.x = acc[r][0] + bz.x; o.y = acc[r][1] + bz.y;
        o.z = acc[r][2] + bz.z; o.w = acc[r][3] + bz.w;
        *(float4*)&gates[(size_t)(bm + ty * 2 + r) * N1_ + bn + tx * 4] = o;
    }
}

// elementwise LSTM update; grid GA_, block HP_
__global__ __launch_bounds__(256) void k_update(const float* __restrict__ gates,
                                                float* __restrict__ h, float* __restrict__ c) {
    const int b = blockIdx.x;
    const int j = threadIdx.x;
    const size_t base = (size_t)b * N1_;
    const float gi = gates[base + j];
    const float gf = gates[base + HP_ + j];
    const float gg = gates[base + 2 * HP_ + j];
    const float go = gates[base + 3 * HP_ + j];
    const float cp = c[(size_t)b * HP_ + j];
    const float cn = sigmoidf_(gf) * cp + sigmoidf_(gi) * tanhf(gg);
    c[(size_t)b * HP_ + j] = cn;
    h[(size_t)b * HP_ + j] = sigmoidf_(go) * tanhf(cn);
}

// ---------------- author stage ----------------
// z_auth[(a*16+g)][j] = b_auth[j] + sum_k h[(g*64+a)][k] * k_auth[k][j]
// grid (2, 256), block 256; 4 batch rows per block
__global__ __launch_bounds__(256) void k_zauth(const float* __restrict__ h,
                                               const float* __restrict__ k_auth,
                                               const float* __restrict__ b_auth,
                                               float* __restrict__ z_auth) {
    const int j = blockIdx.x * 256 + threadIdx.x;
    const int r0 = blockIdx.y * 4;
    float acc0 = b_auth[j], acc1 = acc0, acc2 = acc0, acc3 = acc0;
    for (int k = 0; k < HP_; ++k) {
        const float kp = k_auth[(size_t)k * N2_ + j];
        acc0 += h[(size_t)(r0 + 0) * HP_ + k] * kp;
        acc1 += h[(size_t)(r0 + 1) * HP_ + k] * kp;
        acc2 += h[(size_t)(r0 + 2) * HP_ + k] * kp;
        acc3 += h[(size_t)(r0 + 3) * HP_ + k] * kp;
    }
#pragma unroll
    for (int r = 0; r < 4; ++r) {
        const int b = r0 + r;
        const int g = b >> 6, a = b & 63;
        const float v = (r == 0) ? acc0 : (r == 1) ? acc1 : (r == 2) ? acc2 : acc3;
        z_auth[((size_t)a * G_ + g) * N2_ + j] = v;
    }
}

// author LSTM, one block per group, 64 sequential steps internal.
// block 512: thread j computes gate column j; threads j<128 own h/c element j.
__global__ __launch_bounds__(512) void k_author(const float* __restrict__ z_auth,
                                                const float* __restrict__ r_auth,
                                                float* __restrict__ out) {
    const int g = blockIdx.x;
    const int j = threadIdx.x;   // 0..511
    __shared__ float hs[HA_];
    __shared__ float gs[N2_];
    float cj = 0.f;
    if (j < HA_) hs[j] = 0.f;
    __syncthreads();
    for (int a = 0; a < A_; ++a) {
        float acc = z_auth[((size_t)a * G_ + g) * N2_ + j];
#pragma unroll 4
        for (int k = 0; k < HA_; ++k)
            acc += hs[k] * r_auth[(size_t)k * N2_ + j];
        gs[j] = acc;
        __syncthreads();
        if (j < HA_) {
            const float i_ = sigmoidf_(gs[j]);
            const float f_ = sigmoidf_(gs[j + HA_]);
            const float gg = gs[j + 2 * HA_];
            const float o_ = sigmoidf_(gs[j + 3 * HA_]);
            cj = f_ * cj + i_ * tanhf(gg);
            hs[j] = o_ * tanhf(cj);
        }
        __syncthreads();
    }
    if (j < HA_) out[(size_t)g * HA_ + j] = hs[j];
}

// ---------------- launch ----------------
extern "C" void kernel_launch(void* const* d_in, const int* in_sizes, int n_in,
                              void* d_out, int out_size, void* d_ws, size_t ws_size,
                              hipStream_t stream) {
    const float* x       = (const float*)d_in[0];
    const float* w_embed = (const float*)d_in[1];
    const float* b_embed = (const float*)d_in[2];
    const float* k_post  = (const float*)d_in[3];
    const float* r_post  = (const float*)d_in[4];
    const float* b_post  = (const float*)d_in[5];
    const float* k_auth  = (const float*)d_in[6];
    const float* r_auth  = (const float*)d_in[7];
    const float* b_auth  = (const float*)d_in[8];
    float* out = (float*)d_out;

    float* ws     = (float*)d_ws;
    float* Bmat   = ws + OFF_BMAT;
    float* biasZ  = ws + OFF_BIASZ;
    float* gates  = ws + OFF_GATES;
    float* h      = ws + OFF_H;
    float* c      = ws + OFF_C;
    float* z_auth = ws + OFF_ZAUTH;

    // zero h and c (contiguous)
    hipMemsetAsync(h, 0, (size_t)2 * GA_ * HP_ * sizeof(float), stream);

    // prep: Bmat + biasZ
    k_wk<<<dim3(N1_ / 256, DIN_ / 4), 256, 0, stream>>>(w_embed, k_post, Bmat);
    k_copy_r<<<dim3(256), 256, 0, stream>>>(r_post, Bmat);
    k_bias<<<dim3(N1_ / 256), 256, 0, stream>>>(b_embed, k_post, b_post, biasZ);

    // post LSTM: 32 sequential steps
    for (int t = 0; t < P_; ++t) {
        k_step<<<dim3(N1_ / BN, GA_ / BM), 512, 0, stream>>>(x, Bmat, biasZ, h, gates, t);
        k_update<<<dim3(GA_), HP_, 0, stream>>>(gates, h, c);
    }

    // author stage
    k_zauth<<<dim3(N2_ / 256, GA_ / 4), 256, 0, stream>>>(h, k_auth, b_auth, z_auth);
    k_author<<<dim3(G_), 512, 0, stream>>>(z_auth, r_auth, out);
}

// Round 2
// 1154.368 us; speedup vs baseline: 2.8312x; 2.8312x over previous
//
#include <hip/hip_runtime.h>
#include <cstdint>
#include <cstddef>

// dims
#define G_    16
#define A_    64
#define P_    32
#define DIN_  768
#define DEMB_ 384
#define HP_   256
#define HA_   128
#define GA_   1024      // G_*A_
#define N1_   1024      // 4*HP_
#define K1_   1024      // DIN_+HP_
#define N2_   512       // 4*HA_

typedef float  f32x4  __attribute__((ext_vector_type(4)));
typedef short  short8 __attribute__((ext_vector_type(8)));
typedef unsigned short ushort_t;

__device__ __forceinline__ float sigmoidf_(float x) { return 1.0f / (1.0f + __expf(-x)); }

// ---------------- prep kernels ----------------

// Bmat rows 0..767 : WK[k][j] = sum_d w_embed[k][d] * k_post[d][j]   (f32, [k][n] layout)
__global__ __launch_bounds__(256) void k_wk(const float* __restrict__ w_embed,
                                            const float* __restrict__ k_post,
                                            float* __restrict__ Bmat) {
    int j  = blockIdx.x * 256 + threadIdx.x;
    int k0 = blockIdx.y * 4;
    float acc0 = 0.f, acc1 = 0.f, acc2 = 0.f, acc3 = 0.f;
    for (int d = 0; d < DEMB_; ++d) {
        float kp = k_post[(size_t)d * N1_ + j];
        acc0 += w_embed[(size_t)(k0 + 0) * DEMB_ + d] * kp;
        acc1 += w_embed[(size_t)(k0 + 1) * DEMB_ + d] * kp;
        acc2 += w_embed[(size_t)(k0 + 2) * DEMB_ + d] * kp;
        acc3 += w_embed[(size_t)(k0 + 3) * DEMB_ + d] * kp;
    }
    Bmat[(size_t)(k0 + 0) * N1_ + j] = acc0;
    Bmat[(size_t)(k0 + 1) * N1_ + j] = acc1;
    Bmat[(size_t)(k0 + 2) * N1_ + j] = acc2;
    Bmat[(size_t)(k0 + 3) * N1_ + j] = acc3;
}

// Bmat rows 768..1023 <- r_post
__global__ void k_copy_r(const float* __restrict__ r_post, float* __restrict__ Bmat) {
    int i = blockIdx.x * 256 + threadIdx.x;   // 0..65535
    const float4* src = (const float4*)r_post;
    float4* dst = (float4*)(Bmat + (size_t)DIN_ * N1_);
    dst[i] = src[i];
}

// permuted bias: p = 64*(j>>4) + 16*q + (j&15)  <->  n = (p>>6)*16 + (p&15) + 256*((p>>4)&3)
__global__ __launch_bounds__(256) void k_bias_p(const float* __restrict__ b_embed,
                                                const float* __restrict__ k_post,
                                                const float* __restrict__ b_post,
                                                float* __restrict__ biasZp) {
    int p = blockIdx.x * 256 + threadIdx.x;
    int jgrp = p >> 6, q = (p >> 4) & 3, hl = p & 15;
    int n = jgrp * 16 + hl + q * 256;
    float acc = b_post[n];
    for (int d = 0; d < DEMB_; ++d)
        acc += b_embed[d] * k_post[(size_t)d * N1_ + n];
    biasZp[p] = acc;
}

// transpose + column-permute + split Bmat[k][n] f32 -> BtH/BtL[p][k] bf16(hi/lo)
__global__ __launch_bounds__(256) void k_tsplit(const float* __restrict__ Bmat,
                                                ushort_t* __restrict__ BtH,
                                                ushort_t* __restrict__ BtL) {
    __shared__ float tile[64][65];
    const int tid = threadIdx.x;
    const int p0 = blockIdx.x * 64;
    const int k0 = blockIdx.y * 64;
    const int jgrp = p0 >> 6;
#pragma unroll
    for (int i = 0; i < 16; ++i) {
        int idx = i * 256 + tid;
        int pp = idx & 63, kk = idx >> 6;
        int q = (pp >> 4) & 3, hl = pp & 15;
        int n = jgrp * 16 + hl + q * 256;
        tile[pp][kk] = Bmat[(size_t)(k0 + kk) * N1_ + n];
    }
    __syncthreads();
    const int pp = tid >> 2;
    const int kq = (tid & 3) * 16;
    uint4 hv0, hv1, lv0, lv1;
    ushort_t* hb = (ushort_t*)&hv0;   // hv0,hv1 contiguous? not guaranteed; use two arrays
    ushort_t hbuf[16], lbuf[16];
#pragma unroll
    for (int i = 0; i < 16; ++i) {
        float v = tile[pp][kq + i];
        unsigned uu = __float_as_uint(v);
        ushort_t hu = (ushort_t)(uu >> 16);
        float hf = __uint_as_float((unsigned)hu << 16);
        float rr = v - hf;
        hbuf[i] = hu;
        lbuf[i] = (ushort_t)(__float_as_uint(rr) >> 16);
    }
    (void)hb; (void)hv0; (void)hv1; (void)lv0; (void)lv1;
    size_t obase = (size_t)(p0 + pp) * K1_ + k0 + kq;
    *(uint4*)&BtH[obase]     = *(uint4*)&hbuf[0];
    *(uint4*)&BtH[obase + 8] = *(uint4*)&hbuf[8];
    *(uint4*)&BtL[obase]     = *(uint4*)&lbuf[0];
    *(uint4*)&BtL[obase + 8] = *(uint4*)&lbuf[8];
}

// ---------------- post-LSTM fused step (MFMA 3-pass + in-epilogue LSTM update) ----------------
#define TBM 64
#define TBN 64
#define TBK 32
#define PADK 40   // ushort row stride (80B, 16B-aligned)

__global__ __launch_bounds__(256) void k_step(const float* __restrict__ x,
                                              const ushort_t* __restrict__ BtH,
                                              const ushort_t* __restrict__ BtL,
                                              const float* __restrict__ biasZp,
                                              const float* __restrict__ hin,
                                              float* __restrict__ hout,
                                              float* __restrict__ c, int t) {
    __shared__ union {
        struct { ushort_t AsH[TBM][PADK], AsL[TBM][PADK], BsH[TBN][PADK], BsL[TBN][PADK]; } S;
        float Gs[TBM][68];
    } u;

    const int tid = threadIdx.x;
    const int b0 = blockIdx.y * TBM;      // batch rows
    const int p0 = blockIdx.x * TBN;      // permuted gate cols
    const int srow = tid >> 2;            // staging row 0..63
    const int skq  = (tid & 3) * 8;       // staging k offset
    const int lane = tid & 63;
    const int w = tid >> 6;
    const int wr = (w >> 1) * 32;
    const int wc = (w & 1) * 32;
    const int frc = lane & 15;            // frag row (A) / col (B)
    const int frk = (lane >> 4) * 8;      // frag k offset

    const float bz0 = biasZp[p0 + wc + frc];
    const float bz1 = biasZp[p0 + wc + 16 + frc];

    f32x4 acc[2][2];
#pragma unroll
    for (int i = 0; i < 2; ++i)
#pragma unroll
        for (int j = 0; j < 2; ++j) acc[i][j] = (f32x4)0.0f;

    // A source address for this thread at K-offset k0
    auto aAddr = [&](int k0) -> const float* {
        int k = k0 + skq;
        if (k < DIN_) return &x[((size_t)(b0 + srow) * P_ + t) * DIN_ + k];
        return &hin[(size_t)(b0 + srow) * HP_ + (k - DIN_)];
    };
    const size_t bRow = (size_t)(p0 + srow) * K1_;

    const int NK = K1_ / TBK;  // 32
    const float* ap = aAddr(0);
    float4 aC0 = *(const float4*)ap;
    float4 aC1 = *(const float4*)(ap + 4);
    uint4 bC0 = *(const uint4*)&BtH[bRow + skq];
    uint4 bC1 = *(const uint4*)&BtL[bRow + skq];

    for (int kt = 0; kt < NK; ++kt) {
        // prefetch next K-tile (clamped; last iter redundant)
        const int ktn = (kt + 1 < NK) ? (kt + 1) : kt;
        const float* apn = aAddr(ktn * TBK);
        float4 aN0 = *(const float4*)apn;
        float4 aN1 = *(const float4*)(apn + 4);
        uint4 bN0 = *(const uint4*)&BtH[bRow + ktn * TBK + skq];
        uint4 bN1 = *(const uint4*)&BtL[bRow + ktn * TBK + skq];

        // split current A 8 floats -> bf16 hi/lo (truncation split)
        uint4 ahv, alv;
        {
            ushort_t* ah = (ushort_t*)&ahv;
            ushort_t* al = (ushort_t*)&alv;
            float av[8] = {aC0.x, aC0.y, aC0.z, aC0.w, aC1.x, aC1.y, aC1.z, aC1.w};
#pragma unroll
            for (int i = 0; i < 8; ++i) {
                unsigned uu = __float_as_uint(av[i]);
                ushort_t hu = (ushort_t)(uu >> 16);
                float hf = __uint_as_float((unsigned)hu << 16);
                float rr = av[i] - hf;
                ah[i] = hu;
                al[i] = (ushort_t)(__float_as_uint(rr) >> 16);
            }
        }

        __syncthreads();   // previous iteration's frag reads complete
        *(uint4*)&u.S.AsH[srow][skq] = ahv;
        *(uint4*)&u.S.AsL[srow][skq] = alv;
        *(uint4*)&u.S.BsH[srow][skq] = bC0;
        *(uint4*)&u.S.BsL[srow][skq] = bC1;
        __syncthreads();

        short8 aH[2], aL[2], bH[2], bL[2];
#pragma unroll
        for (int fm = 0; fm < 2; ++fm) {
            aH[fm] = *(const short8*)&u.S.AsH[wr + fm * 16 + frc][frk];
            aL[fm] = *(const short8*)&u.S.AsL[wr + fm * 16 + frc][frk];
        }
#pragma unroll
        for (int fn = 0; fn < 2; ++fn) {
            bH[fn] = *(const short8*)&u.S.BsH[wc + fn * 16 + frc][frk];
            bL[fn] = *(const short8*)&u.S.BsL[wc + fn * 16 + frc][frk];
        }
#pragma unroll
        for (int fm = 0; fm < 2; ++fm)
#pragma unroll
            for (int fn = 0; fn < 2; ++fn) {
                acc[fm][fn] = __builtin_amdgcn_mfma_f32_16x16x32_bf16(aH[fm], bH[fn], acc[fm][fn], 0, 0, 0);
                acc[fm][fn] = __builtin_amdgcn_mfma_f32_16x16x32_bf16(aH[fm], bL[fn], acc[fm][fn], 0, 0, 0);
                acc[fm][fn] = __builtin_amdgcn_mfma_f32_16x16x32_bf16(aL[fm], bH[fn], acc[fm][fn], 0, 0, 0);
            }

        aC0 = aN0; aC1 = aN1; bC0 = bN0; bC1 = bN1;
    }

    // ---- epilogue: stage gates to LDS, fused LSTM update ----
    __syncthreads();   // last frag reads done before union reuse
#pragma unroll
    for (int fm = 0; fm < 2; ++fm)
#pragma unroll
        for (int fn = 0; fn < 2; ++fn)
#pragma unroll
            for (int r = 0; r < 4; ++r) {
                int row = wr + fm * 16 + (lane >> 4) * 4 + r;
                int col = wc + fn * 16 + frc;
                u.Gs[row][col] = acc[fm][fn][r] + (fn ? bz1 : bz0);
            }
    __syncthreads();

    const int n16 = blockIdx.x * 16;   // h-column base
#pragma unroll
    for (int it = 0; it < 4; ++it) {
        int item = it * 256 + tid;
        int row = item >> 4;
        int hl = item & 15;
        float gi = u.Gs[row][hl];
        float gf = u.Gs[row][16 + hl];
        float gg = u.Gs[row][32 + hl];
        float go = u.Gs[row][48 + hl];
        size_t idx = (size_t)(b0 + row) * HP_ + n16 + hl;
        float cp = c[idx];
        float cn = sigmoidf_(gf) * cp + sigmoidf_(gi) * tanhf(gg);
        c[idx] = cn;
        hout[idx] = sigmoidf_(go) * tanhf(cn);
    }
}

// ---------------- author stage ----------------
// z_auth[(a*16+g)][j] = b_auth[j] + sum_k h[(g*64+a)][k] * k_auth[k][j]
__global__ __launch_bounds__(256) void k_zauth(const float* __restrict__ h,
                                               const float* __restrict__ k_auth,
                                               const float* __restrict__ b_auth,
                                               float* __restrict__ z_auth) {
    const int j = blockIdx.x * 256 + threadIdx.x;
    const int r0 = blockIdx.y * 4;
    float acc0 = b_auth[j], acc1 = acc0, acc2 = acc0, acc3 = acc0;
    for (int k = 0; k < HP_; ++k) {
        const float kp = k_auth[(size_t)k * N2_ + j];
        acc0 += h[(size_t)(r0 + 0) * HP_ + k] * kp;
        acc1 += h[(size_t)(r0 + 1) * HP_ + k] * kp;
        acc2 += h[(size_t)(r0 + 2) * HP_ + k] * kp;
        acc3 += h[(size_t)(r0 + 3) * HP_ + k] * kp;
    }
#pragma unroll
    for (int r = 0; r < 4; ++r) {
        const int b = r0 + r;
        const int g = b >> 6, a = b & 63;
        const float v = (r == 0) ? acc0 : (r == 1) ? acc1 : (r == 2) ? acc2 : acc3;
        z_auth[((size_t)a * G_ + g) * N2_ + j] = v;
    }
}

// author LSTM: one block/group, 1024 threads; r_auth held in registers (64 f32/thread).
__global__ __launch_bounds__(1024) void k_author(const float* __restrict__ z_auth,
                                                 const float* __restrict__ r_auth,
                                                 float* __restrict__ out) {
    const int g = blockIdx.x;
    const int tid = threadIdx.x;
    const int j = tid & 511;
    const int kh = tid >> 9;   // 0 or 1: which half of k

    __shared__ float hs[HA_];
    __shared__ float parts[2][512];

    float rc[64];
#pragma unroll
    for (int kk = 0; kk < 64; ++kk)
        rc[kk] = r_auth[(size_t)(kh * 64 + kk) * N2_ + j];

    float cj = 0.f;
    if (tid < HA_) hs[tid] = 0.f;
    __syncthreads();

    for (int a = 0; a < A_; ++a) {
        float acc = (kh == 0) ? z_auth[((size_t)a * G_ + g) * N2_ + j] : 0.f;
#pragma unroll
        for (int kk = 0; kk < 64; ++kk)
            acc += hs[kh * 64 + kk] * rc[kk];
        parts[kh][j] = acc;
        __syncthreads();
        if (tid < HA_) {
            float gi = parts[0][tid]       + parts[1][tid];
            float gf = parts[0][tid + 128] + parts[1][tid + 128];
            float gg = parts[0][tid + 256] + parts[1][tid + 256];
            float go = parts[0][tid + 384] + parts[1][tid + 384];
            cj = sigmoidf_(gf) * cj + sigmoidf_(gi) * tanhf(gg);
            hs[tid] = sigmoidf_(go) * tanhf(cj);
        }
        __syncthreads();
    }
    if (tid < HA_) out[(size_t)g * HA_ + tid] = hs[tid];
}

// ---------------- launch ----------------
extern "C" void kernel_launch(void* const* d_in, const int* in_sizes, int n_in,
                              void* d_out, int out_size, void* d_ws, size_t ws_size,
                              hipStream_t stream) {
    const float* x       = (const float*)d_in[0];
    const float* w_embed = (const float*)d_in[1];
    const float* b_embed = (const float*)d_in[2];
    const float* k_post  = (const float*)d_in[3];
    const float* r_post  = (const float*)d_in[4];
    const float* b_post  = (const float*)d_in[5];
    const float* k_auth  = (const float*)d_in[6];
    const float* r_auth  = (const float*)d_in[7];
    const float* b_auth  = (const float*)d_in[8];
    float* out = (float*)d_out;

    char* w = (char*)d_ws;
    float*    Bmat   = (float*)(w);                                   // 4 MB  [k][n] f32
    ushort_t* BtH    = (ushort_t*)(w + (4ull  << 20));                // 2 MB  [p][k] bf16 hi
    ushort_t* BtL    = (ushort_t*)(w + (6ull  << 20));                // 2 MB  [p][k] bf16 lo
    float*    biasZp = (float*)(w + (8ull  << 20));                   // 4 KB (reserve 64 KB)
    float*    h0     = (float*)(w + (8ull  << 20) + (64ull << 10));   // 1 MB
    float*    c      = (float*)(w + (9ull  << 20) + (64ull << 10));   // 1 MB (adjacent to h0)
    float*    h1     = (float*)(w + (10ull << 20) + (64ull << 10));   // 1 MB
    float*    z_auth = (float*)(w + (11ull << 20) + (64ull << 10));   // 2 MB

    // zero h0 and c (adjacent, one memset); h1 is written before first read (t=0 epilogue)
    hipMemsetAsync(h0, 0, (size_t)2 * GA_ * HP_ * sizeof(float), stream);

    // prep
    k_wk    <<<dim3(N1_ / 256, DIN_ / 4), 256, 0, stream>>>(w_embed, k_post, Bmat);
    k_copy_r<<<dim3(256), 256, 0, stream>>>(r_post, Bmat);
    k_bias_p<<<dim3(N1_ / 256), 256, 0, stream>>>(b_embed, k_post, b_post, biasZp);
    k_tsplit<<<dim3(16, 16), 256, 0, stream>>>(Bmat, BtH, BtL);

    // post LSTM: 32 fused steps, h ping-pong
    for (int t = 0; t < P_; ++t) {
        const float* hin = (t & 1) ? h1 : h0;
        float*       hob = (t & 1) ? h0 : h1;
        k_step<<<dim3(N1_ / TBN, GA_ / TBM), 256, 0, stream>>>(x, BtH, BtL, biasZp, hin, hob, c, t);
    }
    // after 32 steps, final h is in h0

    // author stage
    k_zauth <<<dim3(N2_ / 256, GA_ / 4), 256, 0, stream>>>(h0, k_auth, b_auth, z_auth);
    k_author<<<dim3(G_), 1024, 0, stream>>>(z_auth, r_auth, out);
}

// Round 3
// 1117.382 us; speedup vs baseline: 2.9249x; 1.0331x over previous
//
#include <hip/hip_runtime.h>
#include <hip/hip_fp16.h>
#include <cstdint>
#include <cstddef>

// dims
#define G_    16
#define A_    64
#define P_    32
#define DIN_  768
#define DEMB_ 384
#define HP_   256
#define HA_   128
#define GA_   1024
#define N1_   1024
#define K1_   1024
#define N2_   512
#define TCH   16          // timesteps per chunk
#define MCH   (GA_*TCH)   // 16384 zgemm rows per chunk

typedef float  f32x4  __attribute__((ext_vector_type(4)));
typedef short  short8 __attribute__((ext_vector_type(8)));
typedef unsigned short ushort_t;

__device__ __forceinline__ float sigmoidf_(float x) { return 1.0f / (1.0f + __expf(-x)); }

__device__ __forceinline__ void splitbf(float v, ushort_t& hi, ushort_t& lo) {
    unsigned uu = __float_as_uint(v);
    hi = (ushort_t)(uu >> 16);
    float rr = v - __uint_as_float(uu & 0xffff0000u);
    lo = (ushort_t)(__float_as_uint(rr) >> 16);
}

// ---------------- prep kernels ----------------

// Bmat rows 0..767 : WK[k][j] = sum_d w_embed[k][d] * k_post[d][j]   (f32, [k][n])
__global__ __launch_bounds__(256) void k_wk(const float* __restrict__ w_embed,
                                            const float* __restrict__ k_post,
                                            float* __restrict__ Bmat) {
    int j  = blockIdx.x * 256 + threadIdx.x;
    int k0 = blockIdx.y * 4;
    float acc0 = 0.f, acc1 = 0.f, acc2 = 0.f, acc3 = 0.f;
    for (int d = 0; d < DEMB_; ++d) {
        float kp = k_post[(size_t)d * N1_ + j];
        acc0 += w_embed[(size_t)(k0 + 0) * DEMB_ + d] * kp;
        acc1 += w_embed[(size_t)(k0 + 1) * DEMB_ + d] * kp;
        acc2 += w_embed[(size_t)(k0 + 2) * DEMB_ + d] * kp;
        acc3 += w_embed[(size_t)(k0 + 3) * DEMB_ + d] * kp;
    }
    Bmat[(size_t)(k0 + 0) * N1_ + j] = acc0;
    Bmat[(size_t)(k0 + 1) * N1_ + j] = acc1;
    Bmat[(size_t)(k0 + 2) * N1_ + j] = acc2;
    Bmat[(size_t)(k0 + 3) * N1_ + j] = acc3;
}

__global__ void k_copy_r(const float* __restrict__ r_post, float* __restrict__ Bmat) {
    int i = blockIdx.x * 256 + threadIdx.x;
    const float4* src = (const float4*)r_post;
    float4* dst = (float4*)(Bmat + (size_t)DIN_ * N1_);
    dst[i] = src[i];
}

// permuted bias: p = 64*(j>>4) + 16*q + (j&15)
__global__ __launch_bounds__(256) void k_bias_p(const float* __restrict__ b_embed,
                                                const float* __restrict__ k_post,
                                                const float* __restrict__ b_post,
                                                float* __restrict__ biasZp) {
    int p = blockIdx.x * 256 + threadIdx.x;
    int jgrp = p >> 6, q = (p >> 4) & 3, hl = p & 15;
    int n = jgrp * 16 + hl + q * 256;
    float acc = b_post[n];
    for (int d = 0; d < DEMB_; ++d)
        acc += b_embed[d] * k_post[(size_t)d * N1_ + n];
    biasZp[p] = acc;
}

// transpose + column-permute + split Bmat[k][n] -> BtH/BtL[p][k] bf16 hi/lo
__global__ __launch_bounds__(256) void k_tsplit(const float* __restrict__ Bmat,
                                                ushort_t* __restrict__ BtH,
                                                ushort_t* __restrict__ BtL) {
    __shared__ float tile[64][65];
    const int tid = threadIdx.x;
    const int p0 = blockIdx.x * 64;
    const int k0 = blockIdx.y * 64;
    const int jgrp = p0 >> 6;
#pragma unroll
    for (int i = 0; i < 16; ++i) {
        int idx = i * 256 + tid;
        int pp = idx & 63, kk = idx >> 6;
        int q = (pp >> 4) & 3, hl = pp & 15;
        int n = jgrp * 16 + hl + q * 256;
        tile[pp][kk] = Bmat[(size_t)(k0 + kk) * N1_ + n];
    }
    __syncthreads();
    const int pp = tid >> 2;
    const int kq = (tid & 3) * 16;
    ushort_t hbuf[16], lbuf[16];
#pragma unroll
    for (int i = 0; i < 16; ++i) splitbf(tile[pp][kq + i], hbuf[i], lbuf[i]);
    size_t obase = (size_t)(p0 + pp) * K1_ + k0 + kq;
    *(uint4*)&BtH[obase]     = *(uint4*)&hbuf[0];
    *(uint4*)&BtH[obase + 8] = *(uint4*)&hbuf[8];
    *(uint4*)&BtL[obase]     = *(uint4*)&lbuf[0];
    *(uint4*)&BtL[obase + 8] = *(uint4*)&lbuf[8];
}

// ---------------- Z precompute GEMM: Z = x @ WK + bias (3-pass bf16, fp16 out) ----------------
#define ZBM 128
#define ZBN 256
#define ZBK 32
#define ZPAD 40

__global__ __launch_bounds__(512, 2) void k_zgemm(const float* __restrict__ x,
                                                  const ushort_t* __restrict__ BtH,
                                                  const ushort_t* __restrict__ BtL,
                                                  const float* __restrict__ biasZp,
                                                  __half* __restrict__ Zh, int tbase) {
    __shared__ union {
        struct { ushort_t AsH[ZBM][ZPAD], AsL[ZBM][ZPAD], BsH[ZBN][ZPAD], BsL[ZBN][ZPAD]; } S;
        __half Hs[64][264];
    } u;

    const int bid = blockIdx.x;                   // 0..511
    const int wg  = (bid & 7) * 64 + (bid >> 3);  // XCD swizzle (512 % 8 == 0)
    const int bm  = (wg & 127) * ZBM;
    const int bn  = (wg >> 7) * ZBN;
    const int tid = threadIdx.x;

    const int arow = tid >> 2, akq = (tid & 3) * 8;
    const int brow = tid >> 1, bkq = (tid & 1) * 16;
    const int lane = tid & 63, w = tid >> 6;
    const int wm = (w >> 2) * 64, wn = (w & 3) * 64;
    const int frc = lane & 15, frk = (lane >> 4) * 8;

    const int crow = bm + arow;
    const size_t xrow = (size_t)(crow >> 4) * P_ + tbase + (crow & 15);
    const float*    aptr = &x[xrow * DIN_ + akq];
    const ushort_t* bhp  = &BtH[(size_t)(bn + brow) * K1_ + bkq];
    const ushort_t* blp  = &BtL[(size_t)(bn + brow) * K1_ + bkq];

    f32x4 acc[4][4];
#pragma unroll
    for (int i = 0; i < 4; ++i)
#pragma unroll
        for (int j = 0; j < 4; ++j) acc[i][j] = (f32x4)0.0f;

    float4 a0 = *(const float4*)aptr;
    float4 a1 = *(const float4*)(aptr + 4);
    uint4 bh0 = *(const uint4*)bhp;
    uint4 bh1 = *(const uint4*)(bhp + 8);
    uint4 bl0 = *(const uint4*)blp;
    uint4 bl1 = *(const uint4*)(blp + 8);

    const int NK = DIN_ / ZBK;   // 24
    for (int kt = 0; kt < NK; ++kt) {
        const int kn = (kt + 1 < NK) ? (kt + 1) * ZBK : kt * ZBK;
        float4 na0 = *(const float4*)(aptr + kn);
        float4 na1 = *(const float4*)(aptr + kn + 4);
        uint4 nbh0 = *(const uint4*)(bhp + kn);
        uint4 nbh1 = *(const uint4*)(bhp + kn + 8);
        uint4 nbl0 = *(const uint4*)(blp + kn);
        uint4 nbl1 = *(const uint4*)(blp + kn + 8);

        uint4 ahv, alv;
        {
            ushort_t* ah = (ushort_t*)&ahv;
            ushort_t* al = (ushort_t*)&alv;
            float av[8] = {a0.x,a0.y,a0.z,a0.w,a1.x,a1.y,a1.z,a1.w};
#pragma unroll
            for (int i = 0; i < 8; ++i) splitbf(av[i], ah[i], al[i]);
        }

        __syncthreads();
        *(uint4*)&u.S.AsH[arow][akq]     = ahv;
        *(uint4*)&u.S.AsL[arow][akq]     = alv;
        *(uint4*)&u.S.BsH[brow][bkq]     = bh0;
        *(uint4*)&u.S.BsH[brow][bkq + 8] = bh1;
        *(uint4*)&u.S.BsL[brow][bkq]     = bl0;
        *(uint4*)&u.S.BsL[brow][bkq + 8] = bl1;
        __syncthreads();

        short8 bHf[4], bLf[4];
#pragma unroll
        for (int fn = 0; fn < 4; ++fn) {
            bHf[fn] = *(const short8*)&u.S.BsH[wn + fn * 16 + frc][frk];
            bLf[fn] = *(const short8*)&u.S.BsL[wn + fn * 16 + frc][frk];
        }
#pragma unroll
        for (int fm = 0; fm < 4; ++fm) {
            short8 aH = *(const short8*)&u.S.AsH[wm + fm * 16 + frc][frk];
            short8 aL = *(const short8*)&u.S.AsL[wm + fm * 16 + frc][frk];
#pragma unroll
            for (int fn = 0; fn < 4; ++fn)
                acc[fm][fn] = __builtin_amdgcn_mfma_f32_16x16x32_bf16(aH, bHf[fn], acc[fm][fn], 0, 0, 0);
#pragma unroll
            for (int fn = 0; fn < 4; ++fn)
                acc[fm][fn] = __builtin_amdgcn_mfma_f32_16x16x32_bf16(aH, bLf[fn], acc[fm][fn], 0, 0, 0);
#pragma unroll
            for (int fn = 0; fn < 4; ++fn)
                acc[fm][fn] = __builtin_amdgcn_mfma_f32_16x16x32_bf16(aL, bHf[fn], acc[fm][fn], 0, 0, 0);
        }
        a0 = na0; a1 = na1; bh0 = nbh0; bh1 = nbh1; bl0 = nbl0; bl1 = nbl1;
    }

    float bzv[4];
#pragma unroll
    for (int fn = 0; fn < 4; ++fn) bzv[fn] = biasZp[bn + wn + fn * 16 + frc];

#pragma unroll
    for (int half = 0; half < 2; ++half) {
        __syncthreads();
        if ((w >> 2) == half) {
#pragma unroll
            for (int fm = 0; fm < 4; ++fm)
#pragma unroll
                for (int fn = 0; fn < 4; ++fn)
#pragma unroll
                    for (int r = 0; r < 4; ++r) {
                        int rl = fm * 16 + (lane >> 4) * 4 + r;
                        int cl = wn + fn * 16 + frc;
                        u.Hs[rl][cl] = __float2half(acc[fm][fn][r] + bzv[fn]);
                    }
        }
        __syncthreads();
#pragma unroll
        for (int i = 0; i < 4; ++i) {
            int id = i * 512 + tid;
            int r = id >> 5, cc = (id & 31) * 8;
            *(uint4*)&Zh[(size_t)(bm + half * 64 + r) * N1_ + bn + cc] = *(const uint4*)&u.Hs[r][cc];
        }
    }
}

// ---------------- persistent recurrence: gates = Z[t] + h @ r_post; fused LSTM ----------------
// 256 blocks (1/CU, 85KB LDS forces it), 16 closed groups of 16 blocks (same by).
__global__ __launch_bounds__(256) void k_rec(const __half* __restrict__ Zh,
                                             const ushort_t* __restrict__ BtH,
                                             const ushort_t* __restrict__ BtL,
                                             ushort_t* __restrict__ hH0, ushort_t* __restrict__ hL0,
                                             ushort_t* __restrict__ hH1, ushort_t* __restrict__ hL1,
                                             float* __restrict__ hF32,
                                             float* __restrict__ c,
                                             int* __restrict__ flags, int tbase) {
    __shared__ ushort_t RsH[64][264];
    __shared__ ushort_t RsL[64][264];
    __shared__ float Gs[64][68];

    const int tid = threadIdx.x;
    const int blk = blockIdx.x;
    const int bx = blk & 15, by = blk >> 4;
    const int p0 = bx * 64, b0 = by * 64;
    const int lane = tid & 63, w = tid >> 6;
    const int wr = (w >> 1) * 32, wc = (w & 1) * 32;
    const int frc = lane & 15, frk = (lane >> 4) * 8;

    {   // load this block's R slice (rows p0..p0+63, k 768..1023) hi/lo into LDS, once
        const int pl = tid >> 2, kc = (tid & 3) * 64;
#pragma unroll
        for (int i = 0; i < 8; ++i) {
            int k = kc + i * 8;
            *(uint4*)&RsH[pl][k] = *(const uint4*)&BtH[(size_t)(p0 + pl) * K1_ + DIN_ + k];
            *(uint4*)&RsL[pl][k] = *(const uint4*)&BtL[(size_t)(p0 + pl) * K1_ + DIN_ + k];
        }
    }
    __syncthreads();

    ushort_t* hHb[2] = {hH0, hH1};
    ushort_t* hLb[2] = {hL0, hL1};

    for (int tt = 0; tt < TCH; ++tt) {
        const int t = tbase + tt;
        f32x4 acc[2][2];
#pragma unroll
        for (int i = 0; i < 2; ++i)
#pragma unroll
            for (int j = 0; j < 2; ++j) acc[i][j] = (f32x4)0.0f;

        if (t > 0) {
            if (tid == 0) {
                volatile int* fp = &flags[by * P_ + (t - 1)];
                while (__hip_atomic_load(fp, __ATOMIC_ACQUIRE, __HIP_MEMORY_SCOPE_AGENT) < 16)
                    __builtin_amdgcn_s_sleep(8);
            }
            __syncthreads();
            const ushort_t* hH = hHb[(t - 1) & 1];
            const ushort_t* hL = hLb[(t - 1) & 1];
#pragma unroll
            for (int kt = 0; kt < HP_ / 32; ++kt) {
                short8 bh[2], bl[2], ah[2], al[2];
#pragma unroll
                for (int fn = 0; fn < 2; ++fn) {
                    bh[fn] = *(const short8*)&RsH[wc + fn * 16 + frc][kt * 32 + frk];
                    bl[fn] = *(const short8*)&RsL[wc + fn * 16 + frc][kt * 32 + frk];
                }
#pragma unroll
                for (int fm = 0; fm < 2; ++fm) {
                    size_t hoff = (size_t)(b0 + wr + fm * 16 + frc) * HP_ + kt * 32 + frk;
                    ah[fm] = *(const short8*)&hH[hoff];
                    al[fm] = *(const short8*)&hL[hoff];
                }
#pragma unroll
                for (int fm = 0; fm < 2; ++fm)
#pragma unroll
                    for (int fn = 0; fn < 2; ++fn) {
                        acc[fm][fn] = __builtin_amdgcn_mfma_f32_16x16x32_bf16(ah[fm], bh[fn], acc[fm][fn], 0, 0, 0);
                        acc[fm][fn] = __builtin_amdgcn_mfma_f32_16x16x32_bf16(ah[fm], bl[fn], acc[fm][fn], 0, 0, 0);
                        acc[fm][fn] = __builtin_amdgcn_mfma_f32_16x16x32_bf16(al[fm], bh[fn], acc[fm][fn], 0, 0, 0);
                    }
            }
        }

        __syncthreads();   // previous step's Gs reads complete
#pragma unroll
        for (int fm = 0; fm < 2; ++fm)
#pragma unroll
            for (int fn = 0; fn < 2; ++fn)
#pragma unroll
                for (int r = 0; r < 4; ++r)
                    Gs[wr + fm * 16 + (lane >> 4) * 4 + r][wc + fn * 16 + frc] = acc[fm][fn][r];
        __syncthreads();

        ushort_t* hHo = hHb[t & 1];
        ushort_t* hLo = hLb[t & 1];
#pragma unroll
        for (int it = 0; it < 4; ++it) {
            int item = it * 256 + tid;
            int row = item >> 4, hl = item & 15;
            size_t zrow = ((size_t)(b0 + row) * TCH + tt) * N1_ + p0 + hl;
            float gi = Gs[row][hl]      + __half2float(Zh[zrow]);
            float gf = Gs[row][16 + hl] + __half2float(Zh[zrow + 16]);
            float gg = Gs[row][32 + hl] + __half2float(Zh[zrow + 32]);
            float go = Gs[row][48 + hl] + __half2float(Zh[zrow + 48]);
            size_t idx = (size_t)(b0 + row) * HP_ + bx * 16 + hl;
            float cp = (t == 0) ? 0.f : c[idx];
            float cn = sigmoidf_(gf) * cp + sigmoidf_(gi) * tanhf(gg);
            c[idx] = cn;
            float hv = sigmoidf_(go) * tanhf(cn);
            ushort_t hu, lu; splitbf(hv, hu, lu);
            hHo[idx] = hu; hLo[idx] = lu;
            if (t == P_ - 1) hF32[idx] = hv;
        }
        __syncthreads();   // all h writes done before signaling
        if (tid == 0 && t < P_ - 1) {
            __threadfence();
            __hip_atomic_fetch_add(&flags[by * P_ + t], 1, __ATOMIC_RELEASE, __HIP_MEMORY_SCOPE_AGENT);
        }
    }
}

// ---------------- author stage ----------------
__global__ __launch_bounds__(256) void k_zauth(const float* __restrict__ h,
                                               const float* __restrict__ k_auth,
                                               const float* __restrict__ b_auth,
                                               float* __restrict__ z_auth) {
    const int j = blockIdx.x * 256 + threadIdx.x;
    const int r0 = blockIdx.y * 4;
    float acc0 = b_auth[j], acc1 = acc0, acc2 = acc0, acc3 = acc0;
    for (int k = 0; k < HP_; ++k) {
        const float kp = k_auth[(size_t)k * N2_ + j];
        acc0 += h[(size_t)(r0 + 0) * HP_ + k] * kp;
        acc1 += h[(size_t)(r0 + 1) * HP_ + k] * kp;
        acc2 += h[(size_t)(r0 + 2) * HP_ + k] * kp;
        acc3 += h[(size_t)(r0 + 3) * HP_ + k] * kp;
    }
#pragma unroll
    for (int r = 0; r < 4; ++r) {
        const int b = r0 + r;
        const int g = b >> 6, a = b & 63;
        const float v = (r == 0) ? acc0 : (r == 1) ? acc1 : (r == 2) ? acc2 : acc3;
        z_auth[((size_t)a * G_ + g) * N2_ + j] = v;
    }
}

// author LSTM: 16 blocks x 1024 thr; r_auth in regs; pair-shfl k-reduce.
__global__ __launch_bounds__(1024) void k_author(const float* __restrict__ z_auth,
                                                 const float* __restrict__ r_auth,
                                                 float* __restrict__ out) {
    const int g = blockIdx.x;
    const int tid = threadIdx.x;
    const int j = tid >> 1;     // gate column 0..511
    const int kh = tid & 1;     // k half

    __shared__ float hs[HA_];
    __shared__ float gs[N2_];

    float rc[64];
#pragma unroll
    for (int kk = 0; kk < 64; ++kk)
        rc[kk] = r_auth[(size_t)(kh * 64 + kk) * N2_ + j];

    float cj = 0.f;
    if (tid < HA_) hs[tid] = 0.f;
    __syncthreads();

    for (int a = 0; a < A_; ++a) {
        float acc = kh ? 0.f : z_auth[((size_t)a * G_ + g) * N2_ + j];
#pragma unroll
        for (int kk = 0; kk < 64; ++kk)
            acc += hs[kh * 64 + kk] * rc[kk];
        acc += __shfl_xor(acc, 1);
        if (!kh) gs[j] = acc;
        __syncthreads();
        if (tid < HA_) {
            const float i_ = sigmoidf_(gs[tid]);
            const float f_ = sigmoidf_(gs[tid + 128]);
            const float gg = gs[tid + 256];
            const float o_ = sigmoidf_(gs[tid + 384]);
            cj = f_ * cj + i_ * tanhf(gg);
            hs[tid] = o_ * tanhf(cj);
        }
        __syncthreads();
    }
    if (tid < HA_) out[(size_t)g * HA_ + tid] = hs[tid];
}

// ---------------- launch ----------------
extern "C" void kernel_launch(void* const* d_in, const int* in_sizes, int n_in,
                              void* d_out, int out_size, void* d_ws, size_t ws_size,
                              hipStream_t stream) {
    const float* x       = (const float*)d_in[0];
    const float* w_embed = (const float*)d_in[1];
    const float* b_embed = (const float*)d_in[2];
    const float* k_post  = (const float*)d_in[3];
    const float* r_post  = (const float*)d_in[4];
    const float* b_post  = (const float*)d_in[5];
    const float* k_auth  = (const float*)d_in[6];
    const float* r_auth  = (const float*)d_in[7];
    const float* b_auth  = (const float*)d_in[8];
    float* out = (float*)d_out;

    char* w = (char*)d_ws;
    __half*   Zh     = (__half*)(w);                       // 32 MB (chunked)
    float*    Bmat   = (float*)(w + 33554432ull);          // 4 MB
    ushort_t* BtH    = (ushort_t*)(w + 37748736ull);       // 2 MB
    ushort_t* BtL    = (ushort_t*)(w + 39845888ull);       // 2 MB
    float*    biasZp = (float*)(w + 41943040ull);          // 64 KB reserved
    ushort_t* hH0    = (ushort_t*)(w + 42008576ull);       // 512 KB
    ushort_t* hL0    = (ushort_t*)(w + 42532864ull);
    ushort_t* hH1    = (ushort_t*)(w + 43057152ull);
    ushort_t* hL1    = (ushort_t*)(w + 43581440ull);
    float*    hF32   = (float*)(w + 44105728ull);          // 1 MB
    float*    c      = (float*)(w + 45154304ull);          // 1 MB
    float*    z_auth = (float*)(w + 46202880ull);          // 2 MB
    int*      flags  = (int*)(w + 48300032ull);            // 2 KB

    hipMemsetAsync(flags, 0, 16 * P_ * sizeof(int), stream);

    // prep
    k_wk    <<<dim3(N1_ / 256, DIN_ / 4), 256, 0, stream>>>(w_embed, k_post, Bmat);
    k_copy_r<<<dim3(256), 256, 0, stream>>>(r_post, Bmat);
    k_bias_p<<<dim3(N1_ / 256), 256, 0, stream>>>(b_embed, k_post, b_post, biasZp);
    k_tsplit<<<dim3(16, 16), 256, 0, stream>>>(Bmat, BtH, BtL);

    // two chunks of 16 timesteps: big Z GEMM then persistent recurrence
    for (int ch = 0; ch < 2; ++ch) {
        k_zgemm<<<dim3(512), 512, 0, stream>>>(x, BtH, BtL, biasZp, Zh, ch * TCH);
        k_rec  <<<dim3(256), 256, 0, stream>>>(Zh, BtH, BtL, hH0, hL0, hH1, hL1,
                                               hF32, c, flags, ch * TCH);
    }

    // author stage
    k_zauth <<<dim3(N2_ / 256, GA_ / 4), 256, 0, stream>>>(hF32, k_auth, b_auth, z_auth);
    k_author<<<dim3(G_), 1024, 0, stream>>>(z_auth, r_auth, out);
}

// Round 4
// 891.358 us; speedup vs baseline: 3.6665x; 1.2536x over previous
//
#include <hip/hip_runtime.h>
#include <cstdint>
#include <cstddef>

// dims
#define G_    16
#define A_    64
#define P_    32
#define DIN_  768
#define DEMB_ 384
#define HP_   256
#define HA_   128
#define GA_   1024
#define N1_   1024
#define N2_   512
#define TCH   16          // timesteps per chunk

typedef float    f32x4   __attribute__((ext_vector_type(4)));
typedef _Float16 half8_t __attribute__((ext_vector_type(8)));
typedef _Float16 half4_t __attribute__((ext_vector_type(4)));

__device__ __forceinline__ float sigmoidf_(float x) { return 1.0f / (1.0f + __expf(-x)); }

// ---------------- prep kernels ----------------

// Bmat[k][n] = sum_d w_embed[k][d] * k_post[d][n]   (f32, 768x1024)
__global__ __launch_bounds__(256) void k_wk(const float* __restrict__ w_embed,
                                            const float* __restrict__ k_post,
                                            float* __restrict__ Bmat) {
    int j  = blockIdx.x * 256 + threadIdx.x;
    int k0 = blockIdx.y * 4;
    float acc0 = 0.f, acc1 = 0.f, acc2 = 0.f, acc3 = 0.f;
    for (int d = 0; d < DEMB_; ++d) {
        float kp = k_post[(size_t)d * N1_ + j];
        acc0 += w_embed[(size_t)(k0 + 0) * DEMB_ + d] * kp;
        acc1 += w_embed[(size_t)(k0 + 1) * DEMB_ + d] * kp;
        acc2 += w_embed[(size_t)(k0 + 2) * DEMB_ + d] * kp;
        acc3 += w_embed[(size_t)(k0 + 3) * DEMB_ + d] * kp;
    }
    Bmat[(size_t)(k0 + 0) * N1_ + j] = acc0;
    Bmat[(size_t)(k0 + 1) * N1_ + j] = acc1;
    Bmat[(size_t)(k0 + 2) * N1_ + j] = acc2;
    Bmat[(size_t)(k0 + 3) * N1_ + j] = acc3;
}

// permuted bias: p = 64*(n>>4) + 16*((n>>8)) ... inverse: n = (p>>6)*16 + (p&15) + 256*((p>>4)&3)
__global__ __launch_bounds__(256) void k_bias_p(const float* __restrict__ b_embed,
                                                const float* __restrict__ k_post,
                                                const float* __restrict__ b_post,
                                                float* __restrict__ biasZp) {
    int p = blockIdx.x * 256 + threadIdx.x;
    int n = (p >> 6) * 16 + (p & 15) + 256 * ((p >> 4) & 3);
    float acc = b_post[n];
    for (int d = 0; d < DEMB_; ++d)
        acc += b_embed[d] * k_post[(size_t)d * N1_ + n];
    biasZp[p] = acc;
}

// transpose + permute Bmat[k][n] f32 -> Bt16[p][k] fp16 (k<768 only)
__global__ __launch_bounds__(256) void k_t16(const float* __restrict__ Bmat,
                                             _Float16* __restrict__ Bt16) {
    __shared__ float tile[64][65];
    const int tid = threadIdx.x;
    const int p0 = blockIdx.x * 64;
    const int k0 = blockIdx.y * 64;
    const int jgrp = p0 >> 6;
#pragma unroll
    for (int i = 0; i < 16; ++i) {
        int idx = i * 256 + tid;
        int pp = idx & 63, kk = idx >> 6;
        int n = jgrp * 16 + (pp & 15) + 256 * ((pp >> 4) & 3);
        tile[pp][kk] = Bmat[(size_t)(k0 + kk) * N1_ + n];
    }
    __syncthreads();
    const int pp = tid >> 2;
    const int kq = (tid & 3) * 16;
    _Float16 buf[16];
#pragma unroll
    for (int i = 0; i < 16; ++i) buf[i] = (_Float16)tile[pp][kq + i];
    _Float16* dst = &Bt16[(size_t)(p0 + pp) * DIN_ + k0 + kq];
    *(half8_t*)dst       = *(half8_t*)&buf[0];
    *(half8_t*)(dst + 8) = *(half8_t*)&buf[8];
}

// r_post -> fragment-major fp16: Bfrag[((pt*8+kt)*64+l)*8+s] = r_post[kt*32+(l>>4)*8+s][n(pt*16+(l&15))]
__global__ __launch_bounds__(256) void k_bfrag(const float* __restrict__ r_post,
                                               _Float16* __restrict__ Bfrag) {
    int idx = blockIdx.x * 256 + threadIdx.x;   // 0..32767
    int pt = idx >> 9;
    int kt = (idx >> 6) & 7;
    int l  = idx & 63;
    int p = pt * 16 + (l & 15);
    int n = (p >> 6) * 16 + (p & 15) + 256 * ((p >> 4) & 3);
    int kb = kt * 32 + (l >> 4) * 8;
    _Float16 buf[8];
#pragma unroll
    for (int s = 0; s < 8; ++s) buf[s] = (_Float16)r_post[(size_t)(kb + s) * N1_ + n];
    *(half8_t*)&Bfrag[(size_t)idx * 8] = *(half8_t*)buf;
}

// ---------------- Z GEMM: Z = x @ WK + bias, fp16 2-pass, quadruple-permuted fp16 out ----------------
#define ZBM 128
#define ZBN 256
#define ZBK 32
#define ZPAD 40

__global__ __launch_bounds__(512, 2) void k_zgemm(const float* __restrict__ x,
                                                  const _Float16* __restrict__ Bt16,
                                                  const float* __restrict__ biasZp,
                                                  _Float16* __restrict__ Zq, int tbase) {
    __shared__ union {
        struct { _Float16 AsH[ZBM][ZPAD], AsL[ZBM][ZPAD], Bs[ZBN][ZPAD]; } S;
        _Float16 Hs[64][264];
    } u;

    const int bid = blockIdx.x;                   // 0..511
    const int wg  = (bid & 7) * 64 + (bid >> 3);  // XCD swizzle
    const int bm  = (wg & 127) * ZBM;
    const int bn  = (wg >> 7) * ZBN;
    const int tid = threadIdx.x;

    const int arow = tid >> 2, akq = (tid & 3) * 8;
    const int brow = tid >> 1, bkq = (tid & 1) * 16;
    const int lane = tid & 63, w = tid >> 6;
    const int wm = (w >> 2) * 64, wn = (w & 3) * 64;
    const int frc = lane & 15, frk = (lane >> 4) * 8;

    const int crow = bm + arow;
    const size_t xrow = (size_t)(crow >> 4) * P_ + tbase + (crow & 15);
    const float*    aptr = &x[xrow * DIN_ + akq];
    const _Float16* bptr = &Bt16[(size_t)(bn + brow) * DIN_ + bkq];

    f32x4 acc[4][4];
#pragma unroll
    for (int i = 0; i < 4; ++i)
#pragma unroll
        for (int j = 0; j < 4; ++j) acc[i][j] = (f32x4)0.0f;

    float4 a0 = *(const float4*)aptr;
    float4 a1 = *(const float4*)(aptr + 4);
    uint4  b0 = *(const uint4*)bptr;
    uint4  b1 = *(const uint4*)(bptr + 8);

    const int NK = DIN_ / ZBK;   // 24
    for (int kt = 0; kt < NK; ++kt) {
        const int kn = (kt + 1 < NK) ? (kt + 1) * ZBK : kt * ZBK;
        float4 na0 = *(const float4*)(aptr + kn);
        float4 na1 = *(const float4*)(aptr + kn + 4);
        uint4  nb0 = *(const uint4*)(bptr + kn);
        uint4  nb1 = *(const uint4*)(bptr + kn + 8);

        half8_t ahv, alv;
        {
            float av[8] = {a0.x,a0.y,a0.z,a0.w,a1.x,a1.y,a1.z,a1.w};
#pragma unroll
            for (int i = 0; i < 8; ++i) {
                _Float16 hh = (_Float16)av[i];
                ahv[i] = hh;
                alv[i] = (_Float16)(av[i] - (float)hh);
            }
        }

        __syncthreads();
        *(half8_t*)&u.S.AsH[arow][akq] = ahv;
        *(half8_t*)&u.S.AsL[arow][akq] = alv;
        *(uint4*)&u.S.Bs[brow][bkq]     = b0;
        *(uint4*)&u.S.Bs[brow][bkq + 8] = b1;
        __syncthreads();

        half8_t bf[4];
#pragma unroll
        for (int fn = 0; fn < 4; ++fn)
            bf[fn] = *(const half8_t*)&u.S.Bs[wn + fn * 16 + frc][frk];
#pragma unroll
        for (int fm = 0; fm < 4; ++fm) {
            half8_t aH = *(const half8_t*)&u.S.AsH[wm + fm * 16 + frc][frk];
            half8_t aL = *(const half8_t*)&u.S.AsL[wm + fm * 16 + frc][frk];
#pragma unroll
            for (int fn = 0; fn < 4; ++fn)
                acc[fm][fn] = __builtin_amdgcn_mfma_f32_16x16x32_f16(aH, bf[fn], acc[fm][fn], 0, 0, 0);
#pragma unroll
            for (int fn = 0; fn < 4; ++fn)
                acc[fm][fn] = __builtin_amdgcn_mfma_f32_16x16x32_f16(aL, bf[fn], acc[fm][fn], 0, 0, 0);
        }
        a0 = na0; a1 = na1; b0 = nb0; b1 = nb1;
    }

    float bzv[4];
#pragma unroll
    for (int fn = 0; fn < 4; ++fn) bzv[fn] = biasZp[bn + wn + fn * 16 + frc];

#pragma unroll
    for (int half_ = 0; half_ < 2; ++half_) {
        __syncthreads();
        if ((w >> 2) == half_) {
#pragma unroll
            for (int fm = 0; fm < 4; ++fm)
#pragma unroll
                for (int fn = 0; fn < 4; ++fn)
#pragma unroll
                    for (int r = 0; r < 4; ++r) {
                        int rl = fm * 16 + (lane >> 4) * 4 + r;
                        int cl = wn + fn * 16 + frc;
                        int clp = ((cl >> 6) * 16 + (cl & 15)) * 4 + ((cl >> 4) & 3);
                        u.Hs[rl][clp] = (_Float16)(acc[fm][fn][r] + bzv[fn]);
                    }
        }
        __syncthreads();
#pragma unroll
        for (int i = 0; i < 4; ++i) {
            int id = i * 512 + tid;
            int r = id >> 5, cc = (id & 31) * 8;
            *(uint4*)&Zq[(size_t)(bm + half_ * 64 + r) * N1_ + bn + cc] = *(const uint4*)&u.Hs[r][cc];
        }
    }
}

// ---------------- recurrence: self-contained blocks, 16 rows each, fp16 2-pass ----------------
__global__ __launch_bounds__(256) void k_rec(const _Float16* __restrict__ Zq,
                                             const _Float16* __restrict__ Bfrag,
                                             float* __restrict__ csave,
                                             _Float16* __restrict__ hsave,
                                             float* __restrict__ hF32, int tbase) {
    __shared__ __align__(16) _Float16 hHs[8 * 64 * 8];
    __shared__ __align__(16) _Float16 hLs[8 * 64 * 8];

    const int tid = threadIdx.x, lane = tid & 63, w = tid >> 6;
    const int hl = lane & 15, l4 = lane >> 4;
    const int r0 = blockIdx.x * 16;      // batch-pair base
    const int wc = w * 64;               // h-col base of this wave

    float cst[16];
    if (tbase == 0) {
#pragma unroll
        for (int i = 0; i < 16; ++i) cst[i] = 0.f;
    } else {
#pragma unroll
        for (int i = 0; i < 16; ++i)
            cst[i] = csave[((size_t)blockIdx.x * 256 + tid) * 16 + i];
        const _Float16* hs = &hsave[(size_t)blockIdx.x * 8192];
#pragma unroll
        for (int i = 0; i < 2; ++i) {
            *(half8_t*)&hHs[tid * 16 + i * 8] = *(const half8_t*)&hs[tid * 16 + i * 8];
            *(half8_t*)&hLs[tid * 16 + i * 8] = *(const half8_t*)&hs[4096 + tid * 16 + i * 8];
        }
    }
    __syncthreads();

    for (int tt = 0; tt < TCH; ++tt) {
        const int t = tbase + tt;

        // Z quadruples for this thread's 16 h-elements (issued early)
        half4_t zv[4][4];
#pragma unroll
        for (int g4 = 0; g4 < 4; ++g4)
#pragma unroll
            for (int rr = 0; rr < 4; ++rr) {
                int row = l4 * 4 + rr;
                int cc = wc + g4 * 16 + hl;
                zv[g4][rr] = *(const half4_t*)&Zq[((size_t)(r0 + row) * TCH + tt) * N1_ + cc * 4];
            }

        f32x4 acc[16];
#pragma unroll
        for (int i = 0; i < 16; ++i) acc[i] = (f32x4)0.0f;

        if (t > 0) {
#pragma unroll
            for (int kt = 0; kt < 8; ++kt) {
                half8_t ah = *(const half8_t*)&hHs[(kt * 64 + lane) * 8];
                half8_t al = *(const half8_t*)&hLs[(kt * 64 + lane) * 8];
#pragma unroll
                for (int fn = 0; fn < 16; ++fn) {
                    half8_t b = *(const half8_t*)&Bfrag[(((size_t)(w * 16 + fn) * 8 + kt) * 64 + lane) * 8];
                    acc[fn] = __builtin_amdgcn_mfma_f32_16x16x32_f16(ah, b, acc[fn], 0, 0, 0);
                    acc[fn] = __builtin_amdgcn_mfma_f32_16x16x32_f16(al, b, acc[fn], 0, 0, 0);
                }
            }
        }

        __syncthreads();   // all h reads of this step complete

        const bool last = (t == P_ - 1);
#pragma unroll
        for (int g4 = 0; g4 < 4; ++g4)
#pragma unroll
            for (int rr = 0; rr < 4; ++rr) {
                float gi = acc[g4 * 4 + 0][rr] + (float)zv[g4][rr][0];
                float gf = acc[g4 * 4 + 1][rr] + (float)zv[g4][rr][1];
                float gg = acc[g4 * 4 + 2][rr] + (float)zv[g4][rr][2];
                float go = acc[g4 * 4 + 3][rr] + (float)zv[g4][rr][3];
                int ci = g4 * 4 + rr;
                float cn = sigmoidf_(gf) * cst[ci] + sigmoidf_(gi) * tanhf(gg);
                cst[ci] = cn;
                float hv = sigmoidf_(go) * tanhf(cn);
                int row = l4 * 4 + rr;
                int col = wc + g4 * 16 + hl;
                _Float16 hh = (_Float16)hv;
                _Float16 hlo = (_Float16)(hv - (float)hh);
                int rem = col & 31;
                int lidx = (((col >> 5) * 64) + ((rem >> 3) * 16 + row)) * 8 + (rem & 7);
                hHs[lidx] = hh;
                hLs[lidx] = hlo;
                if (last) hF32[(size_t)(r0 + row) * HP_ + col] = hv;
            }
        __syncthreads();   // h writes visible before next step
    }

    if (tbase == 0) {   // save state for chunk 2
#pragma unroll
        for (int i = 0; i < 16; ++i)
            csave[((size_t)blockIdx.x * 256 + tid) * 16 + i] = cst[i];
        _Float16* hs = &hsave[(size_t)blockIdx.x * 8192];
#pragma unroll
        for (int i = 0; i < 2; ++i) {
            *(half8_t*)&hs[tid * 16 + i * 8]        = *(const half8_t*)&hHs[tid * 16 + i * 8];
            *(half8_t*)&hs[4096 + tid * 16 + i * 8] = *(const half8_t*)&hLs[tid * 16 + i * 8];
        }
    }
}

// ---------------- author stage ----------------
__global__ __launch_bounds__(256) void k_zauth(const float* __restrict__ h,
                                               const float* __restrict__ k_auth,
                                               const float* __restrict__ b_auth,
                                               float* __restrict__ z_auth) {
    const int j = blockIdx.x * 256 + threadIdx.x;
    const int r0 = blockIdx.y * 4;
    float acc0 = b_auth[j], acc1 = acc0, acc2 = acc0, acc3 = acc0;
    for (int k = 0; k < HP_; ++k) {
        const float kp = k_auth[(size_t)k * N2_ + j];
        acc0 += h[(size_t)(r0 + 0) * HP_ + k] * kp;
        acc1 += h[(size_t)(r0 + 1) * HP_ + k] * kp;
        acc2 += h[(size_t)(r0 + 2) * HP_ + k] * kp;
        acc3 += h[(size_t)(r0 + 3) * HP_ + k] * kp;
    }
#pragma unroll
    for (int r = 0; r < 4; ++r) {
        const int b = r0 + r;
        const int g = b >> 6, a = b & 63;
        const float v = (r == 0) ? acc0 : (r == 1) ? acc1 : (r == 2) ? acc2 : acc3;
        z_auth[((size_t)a * G_ + g) * N2_ + j] = v;
    }
}

__global__ __launch_bounds__(1024) void k_author(const float* __restrict__ z_auth,
                                                 const float* __restrict__ r_auth,
                                                 float* __restrict__ out) {
    const int g = blockIdx.x;
    const int tid = threadIdx.x;
    const int j = tid >> 1;     // gate column 0..511
    const int kh = tid & 1;     // k half

    __shared__ float hs[HA_];
    __shared__ float gs[N2_];

    float rc[64];
#pragma unroll
    for (int kk = 0; kk < 64; ++kk)
        rc[kk] = r_auth[(size_t)(kh * 64 + kk) * N2_ + j];

    float cj = 0.f;
    if (tid < HA_) hs[tid] = 0.f;
    __syncthreads();

    for (int a = 0; a < A_; ++a) {
        float acc = kh ? 0.f : z_auth[((size_t)a * G_ + g) * N2_ + j];
#pragma unroll
        for (int kk = 0; kk < 64; ++kk)
            acc += hs[kh * 64 + kk] * rc[kk];
        acc += __shfl_xor(acc, 1);
        if (!kh) gs[j] = acc;
        __syncthreads();
        if (tid < HA_) {
            const float i_ = sigmoidf_(gs[tid]);
            const float f_ = sigmoidf_(gs[tid + 128]);
            const float gg = gs[tid + 256];
            const float o_ = sigmoidf_(gs[tid + 384]);
            cj = f_ * cj + i_ * tanhf(gg);
            hs[tid] = o_ * tanhf(cj);
        }
        __syncthreads();
    }
    if (tid < HA_) out[(size_t)g * HA_ + tid] = hs[tid];
}

// ---------------- launch ----------------
extern "C" void kernel_launch(void* const* d_in, const int* in_sizes, int n_in,
                              void* d_out, int out_size, void* d_ws, size_t ws_size,
                              hipStream_t stream) {
    const float* x       = (const float*)d_in[0];
    const float* w_embed = (const float*)d_in[1];
    const float* b_embed = (const float*)d_in[2];
    const float* k_post  = (const float*)d_in[3];
    const float* r_post  = (const float*)d_in[4];
    const float* b_post  = (const float*)d_in[5];
    const float* k_auth  = (const float*)d_in[6];
    const float* r_auth  = (const float*)d_in[7];
    const float* b_auth  = (const float*)d_in[8];
    float* out = (float*)d_out;

    char* wsb = (char*)d_ws;
    _Float16* Zq     = (_Float16*)(wsb);                        // 32 MB (one chunk)
    float*    Bmat   = (float*)(wsb + (32ull << 20));           // 3 MB
    _Float16* Bt16   = (_Float16*)(wsb + (36ull << 20));        // 1.5 MB
    _Float16* Bfrag  = (_Float16*)(wsb + (38ull << 20));        // 512 KB
    float*    biasZp = (float*)(wsb + (38ull << 20) + (512ull << 10));  // 4 KB
    float*    csave  = (float*)(wsb + (39ull << 20));           // 1 MB
    _Float16* hsave  = (_Float16*)(wsb + (40ull << 20));        // 1 MB
    float*    hF32   = (float*)(wsb + (41ull << 20));           // 1 MB
    float*    z_auth = (float*)(wsb + (42ull << 20));           // 2 MB

    // prep
    k_wk    <<<dim3(N1_ / 256, DIN_ / 4), 256, 0, stream>>>(w_embed, k_post, Bmat);
    k_bias_p<<<dim3(N1_ / 256), 256, 0, stream>>>(b_embed, k_post, b_post, biasZp);
    k_t16   <<<dim3(16, 12), 256, 0, stream>>>(Bmat, Bt16);
    k_bfrag <<<dim3(128), 256, 0, stream>>>(r_post, Bfrag);

    // two chunks of 16 timesteps
    for (int ch = 0; ch < 2; ++ch) {
        k_zgemm<<<dim3(512), 512, 0, stream>>>(x, Bt16, biasZp, Zq, ch * TCH);
        k_rec  <<<dim3(64), 256, 0, stream>>>(Zq, Bfrag, csave, hsave, hF32, ch * TCH);
    }

    // author stage
    k_zauth <<<dim3(N2_ / 256, GA_ / 4), 256, 0, stream>>>(hF32, k_auth, b_auth, z_auth);
    k_author<<<dim3(G_), 1024, 0, stream>>>(z_auth, r_auth, out);
}

// Round 5
// 489.613 us; speedup vs baseline: 6.6751x; 1.8205x over previous
//
#include <hip/hip_runtime.h>
#include <cstdint>
#include <cstddef>

// dims
#define G_    16
#define A_    64
#define P_    32
#define DIN_  768
#define DEMB_ 384
#define HP_   256
#define HA_   128
#define GA_   1024
#define N1_   1024
#define N2_   512
#define TCH   16          // timesteps per chunk

typedef float    f32x4   __attribute__((ext_vector_type(4)));
typedef _Float16 half8_t __attribute__((ext_vector_type(8)));
typedef _Float16 half4_t __attribute__((ext_vector_type(4)));

__device__ __forceinline__ float sigmoidf_(float x) { return 1.0f / (1.0f + __expf(-x)); }
// fast tanh: 2*sigmoid(2x)-1 (v_exp+v_rcp), correct limits at +-inf
__device__ __forceinline__ float tanhf_(float x) { return 2.0f / (1.0f + __expf(-2.0f * x)) - 1.0f; }

// ---------------- prep kernels ----------------

// Bmat[k][n] = sum_d w_embed[k][d] * k_post[d][n]   (f32, 768x1024)
__global__ __launch_bounds__(256) void k_wk(const float* __restrict__ w_embed,
                                            const float* __restrict__ k_post,
                                            float* __restrict__ Bmat) {
    int j  = blockIdx.x * 256 + threadIdx.x;
    int k0 = blockIdx.y * 4;
    float acc0 = 0.f, acc1 = 0.f, acc2 = 0.f, acc3 = 0.f;
    for (int d = 0; d < DEMB_; ++d) {
        float kp = k_post[(size_t)d * N1_ + j];
        acc0 += w_embed[(size_t)(k0 + 0) * DEMB_ + d] * kp;
        acc1 += w_embed[(size_t)(k0 + 1) * DEMB_ + d] * kp;
        acc2 += w_embed[(size_t)(k0 + 2) * DEMB_ + d] * kp;
        acc3 += w_embed[(size_t)(k0 + 3) * DEMB_ + d] * kp;
    }
    Bmat[(size_t)(k0 + 0) * N1_ + j] = acc0;
    Bmat[(size_t)(k0 + 1) * N1_ + j] = acc1;
    Bmat[(size_t)(k0 + 2) * N1_ + j] = acc2;
    Bmat[(size_t)(k0 + 3) * N1_ + j] = acc3;
}

// permuted bias: n = (p>>6)*16 + (p&15) + 256*((p>>4)&3)
__global__ __launch_bounds__(256) void k_bias_p(const float* __restrict__ b_embed,
                                                const float* __restrict__ k_post,
                                                const float* __restrict__ b_post,
                                                float* __restrict__ biasZp) {
    int p = blockIdx.x * 256 + threadIdx.x;
    int n = (p >> 6) * 16 + (p & 15) + 256 * ((p >> 4) & 3);
    float acc = b_post[n];
    for (int d = 0; d < DEMB_; ++d)
        acc += b_embed[d] * k_post[(size_t)d * N1_ + n];
    biasZp[p] = acc;
}

// transpose + permute Bmat[k][n] f32 -> Bt16[p][k] fp16 (k<768 only)
__global__ __launch_bounds__(256) void k_t16(const float* __restrict__ Bmat,
                                             _Float16* __restrict__ Bt16) {
    __shared__ float tile[64][65];
    const int tid = threadIdx.x;
    const int p0 = blockIdx.x * 64;
    const int k0 = blockIdx.y * 64;
    const int jgrp = p0 >> 6;
#pragma unroll
    for (int i = 0; i < 16; ++i) {
        int idx = i * 256 + tid;
        int pp = idx & 63, kk = idx >> 6;
        int n = jgrp * 16 + (pp & 15) + 256 * ((pp >> 4) & 3);
        tile[pp][kk] = Bmat[(size_t)(k0 + kk) * N1_ + n];
    }
    __syncthreads();
    const int pp = tid >> 2;
    const int kq = (tid & 3) * 16;
    _Float16 buf[16];
#pragma unroll
    for (int i = 0; i < 16; ++i) buf[i] = (_Float16)tile[pp][kq + i];
    _Float16* dst = &Bt16[(size_t)(p0 + pp) * DIN_ + k0 + kq];
    *(half8_t*)dst       = *(half8_t*)&buf[0];
    *(half8_t*)(dst + 8) = *(half8_t*)&buf[8];
}

// r_post -> fragment-major fp16
__global__ __launch_bounds__(256) void k_bfrag(const float* __restrict__ r_post,
                                               _Float16* __restrict__ Bfrag) {
    int idx = blockIdx.x * 256 + threadIdx.x;   // 0..32767
    int pt = idx >> 9;
    int kt = (idx >> 6) & 7;
    int l  = idx & 63;
    int p = pt * 16 + (l & 15);
    int n = (p >> 6) * 16 + (p & 15) + 256 * ((p >> 4) & 3);
    int kb = kt * 32 + (l >> 4) * 8;
    _Float16 buf[8];
#pragma unroll
    for (int s = 0; s < 8; ++s) buf[s] = (_Float16)r_post[(size_t)(kb + s) * N1_ + n];
    *(half8_t*)&Bfrag[(size_t)idx * 8] = *(half8_t*)buf;
}

// ---------------- Z GEMM: Z = x @ WK + bias, fp16 2-pass, quadruple-permuted fp16 out ----------------
#define ZBM 128
#define ZBN 256
#define ZBK 32
#define ZPAD 40

__global__ __launch_bounds__(512, 2) void k_zgemm(const float* __restrict__ x,
                                                  const _Float16* __restrict__ Bt16,
                                                  const float* __restrict__ biasZp,
                                                  _Float16* __restrict__ Zq, int tbase) {
    __shared__ union {
        struct { _Float16 AsH[ZBM][ZPAD], AsL[ZBM][ZPAD], Bs[ZBN][ZPAD]; } S;
        _Float16 Hs[64][264];
    } u;

    const int bid = blockIdx.x;                   // 0..511
    const int wg  = (bid & 7) * 64 + (bid >> 3);  // XCD swizzle
    const int bm  = (wg & 127) * ZBM;
    const int bn  = (wg >> 7) * ZBN;
    const int tid = threadIdx.x;

    const int arow = tid >> 2, akq = (tid & 3) * 8;
    const int brow = tid >> 1, bkq = (tid & 1) * 16;
    const int lane = tid & 63, w = tid >> 6;
    const int wm = (w >> 2) * 64, wn = (w & 3) * 64;
    const int frc = lane & 15, frk = (lane >> 4) * 8;

    const int crow = bm + arow;
    const size_t xrow = (size_t)(crow >> 4) * P_ + tbase + (crow & 15);
    const float*    aptr = &x[xrow * DIN_ + akq];
    const _Float16* bptr = &Bt16[(size_t)(bn + brow) * DIN_ + bkq];

    f32x4 acc[4][4];
#pragma unroll
    for (int i = 0; i < 4; ++i)
#pragma unroll
        for (int j = 0; j < 4; ++j) acc[i][j] = (f32x4)0.0f;

    float4 a0 = *(const float4*)aptr;
    float4 a1 = *(const float4*)(aptr + 4);
    uint4  b0 = *(const uint4*)bptr;
    uint4  b1 = *(const uint4*)(bptr + 8);

    const int NK = DIN_ / ZBK;   // 24
    for (int kt = 0; kt < NK; ++kt) {
        const int kn = (kt + 1 < NK) ? (kt + 1) * ZBK : kt * ZBK;
        float4 na0 = *(const float4*)(aptr + kn);
        float4 na1 = *(const float4*)(aptr + kn + 4);
        uint4  nb0 = *(const uint4*)(bptr + kn);
        uint4  nb1 = *(const uint4*)(bptr + kn + 8);

        half8_t ahv, alv;
        {
            float av[8] = {a0.x,a0.y,a0.z,a0.w,a1.x,a1.y,a1.z,a1.w};
#pragma unroll
            for (int i = 0; i < 8; ++i) {
                _Float16 hh = (_Float16)av[i];
                ahv[i] = hh;
                alv[i] = (_Float16)(av[i] - (float)hh);
            }
        }

        __syncthreads();
        *(half8_t*)&u.S.AsH[arow][akq] = ahv;
        *(half8_t*)&u.S.AsL[arow][akq] = alv;
        *(uint4*)&u.S.Bs[brow][bkq]     = b0;
        *(uint4*)&u.S.Bs[brow][bkq + 8] = b1;
        __syncthreads();

        half8_t bf[4];
#pragma unroll
        for (int fn = 0; fn < 4; ++fn)
            bf[fn] = *(const half8_t*)&u.S.Bs[wn + fn * 16 + frc][frk];
#pragma unroll
        for (int fm = 0; fm < 4; ++fm) {
            half8_t aH = *(const half8_t*)&u.S.AsH[wm + fm * 16 + frc][frk];
            half8_t aL = *(const half8_t*)&u.S.AsL[wm + fm * 16 + frc][frk];
#pragma unroll
            for (int fn = 0; fn < 4; ++fn)
                acc[fm][fn] = __builtin_amdgcn_mfma_f32_16x16x32_f16(aH, bf[fn], acc[fm][fn], 0, 0, 0);
#pragma unroll
            for (int fn = 0; fn < 4; ++fn)
                acc[fm][fn] = __builtin_amdgcn_mfma_f32_16x16x32_f16(aL, bf[fn], acc[fm][fn], 0, 0, 0);
        }
        a0 = na0; a1 = na1; b0 = nb0; b1 = nb1;
    }

    float bzv[4];
#pragma unroll
    for (int fn = 0; fn < 4; ++fn) bzv[fn] = biasZp[bn + wn + fn * 16 + frc];

#pragma unroll
    for (int half_ = 0; half_ < 2; ++half_) {
        __syncthreads();
        if ((w >> 2) == half_) {
#pragma unroll
            for (int fm = 0; fm < 4; ++fm)
#pragma unroll
                for (int fn = 0; fn < 4; ++fn)
#pragma unroll
                    for (int r = 0; r < 4; ++r) {
                        int rl = fm * 16 + (lane >> 4) * 4 + r;
                        int cl = wn + fn * 16 + frc;
                        int clp = ((cl >> 6) * 16 + (cl & 15)) * 4 + ((cl >> 4) & 3);
                        u.Hs[rl][clp] = (_Float16)(acc[fm][fn][r] + bzv[fn]);
                    }
        }
        __syncthreads();
#pragma unroll
        for (int i = 0; i < 4; ++i) {
            int id = i * 512 + tid;
            int r = id >> 5, cc = (id & 31) * 8;
            *(uint4*)&Zq[(size_t)(bm + half_ * 64 + r) * N1_ + bn + cc] = *(const uint4*)&u.Hs[r][cc];
        }
    }
}

// ---------------- recurrence: 64 blocks x 1024 threads (16 waves, 4/SIMD) ----------------
// Block owns 16 batch rows, all h/c state in-block. Wave w' owns 16 h-cols
// (fn-subtiles 4w'..4w'+3 = gates 0..3, thread-local quadruples).
__global__ __launch_bounds__(1024, 4) void k_rec(const _Float16* __restrict__ Zq,
                                                 const _Float16* __restrict__ Bfrag,
                                                 float* __restrict__ csave,
                                                 _Float16* __restrict__ hsave,
                                                 float* __restrict__ hF32, int tbase) {
    __shared__ __align__(16) _Float16 hHs[8 * 64 * 8];   // 8KB: h hi, A-fragment layout
    __shared__ __align__(16) _Float16 hLs[8 * 64 * 8];   // 8KB: h residual

    const int tid = threadIdx.x, lane = tid & 63, wv = tid >> 6;   // wv 0..15
    const int hl = lane & 15, l4 = lane >> 4;
    const int r0 = blockIdx.x * 16;       // batch-row base
    const int hc = wv * 16 + hl;          // this thread's h-column
    const size_t bfbase = ((size_t)(4 * wv) * 8) * 64 * 8 + (size_t)lane * 8;

    float cst[4];
    if (tbase == 0) {
#pragma unroll
        for (int i = 0; i < 4; ++i) cst[i] = 0.f;
    } else {
        f32x4 cv = *(const f32x4*)&csave[((size_t)blockIdx.x * 1024 + tid) * 4];
#pragma unroll
        for (int i = 0; i < 4; ++i) cst[i] = cv[i];
        const _Float16* hs = &hsave[(size_t)blockIdx.x * 8192];
        if (tid < 512) *(half8_t*)&hHs[tid * 8] = *(const half8_t*)&hs[tid * 8];
        else           *(half8_t*)&hLs[(tid - 512) * 8] = *(const half8_t*)&hs[4096 + (tid - 512) * 8];
    }
    __syncthreads();

    for (int tt = 0; tt < TCH; ++tt) {
        const int t = tbase + tt;

        // prefetch Z quadruples: gate-quad for (row, hc), rows l4*4+rr
        half4_t zv[4];
#pragma unroll
        for (int rr = 0; rr < 4; ++rr) {
            int row = l4 * 4 + rr;
            zv[rr] = *(const half4_t*)&Zq[((size_t)(r0 + row) * TCH + tt) * N1_ + (size_t)hc * 4];
        }

        f32x4 acc[4];
#pragma unroll
        for (int i = 0; i < 4; ++i) acc[i] = (f32x4)0.0f;

        if (t > 0) {
#pragma unroll
            for (int kt = 0; kt < 8; ++kt) {
                half8_t ah = *(const half8_t*)&hHs[(kt * 64 + lane) * 8];
                half8_t al = *(const half8_t*)&hLs[(kt * 64 + lane) * 8];
#pragma unroll
                for (int q = 0; q < 4; ++q) {
                    half8_t b = *(const half8_t*)&Bfrag[bfbase + (size_t)(q * 8 + kt) * 512];
                    acc[q] = __builtin_amdgcn_mfma_f32_16x16x32_f16(ah, b, acc[q], 0, 0, 0);
                    acc[q] = __builtin_amdgcn_mfma_f32_16x16x32_f16(al, b, acc[q], 0, 0, 0);
                }
            }
        }

        __syncthreads();   // all hHs/hLs reads of this step complete

        const bool last = (t == P_ - 1);
        const int rem = hc & 31;
        const int kt_w = hc >> 5;
#pragma unroll
        for (int rr = 0; rr < 4; ++rr) {
            float gi = acc[0][rr] + (float)zv[rr][0];
            float gf = acc[1][rr] + (float)zv[rr][1];
            float gg = acc[2][rr] + (float)zv[rr][2];
            float go = acc[3][rr] + (float)zv[rr][3];
            float cn = sigmoidf_(gf) * cst[rr] + sigmoidf_(gi) * tanhf_(gg);
            cst[rr] = cn;
            float hv = sigmoidf_(go) * tanhf_(cn);
            int row = l4 * 4 + rr;
            _Float16 hh = (_Float16)hv;
            _Float16 hlo = (_Float16)(hv - (float)hh);
            int lidx = ((kt_w * 64) + ((rem >> 3) * 16 + row)) * 8 + (rem & 7);
            hHs[lidx] = hh;
            hLs[lidx] = hlo;
            if (last) hF32[(size_t)(r0 + row) * HP_ + hc] = hv;
        }
        __syncthreads();   // h writes visible before next step
    }

    if (tbase == 0) {   // save state for chunk 2
        f32x4 cv;
#pragma unroll
        for (int i = 0; i < 4; ++i) cv[i] = cst[i];
        *(f32x4*)&csave[((size_t)blockIdx.x * 1024 + tid) * 4] = cv;
        _Float16* hs = &hsave[(size_t)blockIdx.x * 8192];
        if (tid < 512) *(half8_t*)&hs[tid * 8] = *(const half8_t*)&hHs[tid * 8];
        else           *(half8_t*)&hs[4096 + (tid - 512) * 8] = *(const half8_t*)&hLs[(tid - 512) * 8];
    }
}

// ---------------- author stage ----------------
__global__ __launch_bounds__(256) void k_zauth(const float* __restrict__ h,
                                               const float* __restrict__ k_auth,
                                               const float* __restrict__ b_auth,
                                               float* __restrict__ z_auth) {
    const int j = blockIdx.x * 256 + threadIdx.x;
    const int r0 = blockIdx.y * 4;
    float acc0 = b_auth[j], acc1 = acc0, acc2 = acc0, acc3 = acc0;
    for (int k = 0; k < HP_; ++k) {
        const float kp = k_auth[(size_t)k * N2_ + j];
        acc0 += h[(size_t)(r0 + 0) * HP_ + k] * kp;
        acc1 += h[(size_t)(r0 + 1) * HP_ + k] * kp;
        acc2 += h[(size_t)(r0 + 2) * HP_ + k] * kp;
        acc3 += h[(size_t)(r0 + 3) * HP_ + k] * kp;
    }
#pragma unroll
    for (int r = 0; r < 4; ++r) {
        const int b = r0 + r;
        const int g = b >> 6, a = b & 63;
        const float v = (r == 0) ? acc0 : (r == 1) ? acc1 : (r == 2) ? acc2 : acc3;
        z_auth[((size_t)a * G_ + g) * N2_ + j] = v;
    }
}

__global__ __launch_bounds__(1024) void k_author(const float* __restrict__ z_auth,
                                                 const float* __restrict__ r_auth,
                                                 float* __restrict__ out) {
    const int g = blockIdx.x;
    const int tid = threadIdx.x;
    const int j = tid >> 1;     // gate column 0..511
    const int kh = tid & 1;     // k half

    __shared__ float hs[HA_];
    __shared__ float gs[N2_];

    float rc[64];
#pragma unroll
    for (int kk = 0; kk < 64; ++kk)
        rc[kk] = r_auth[(size_t)(kh * 64 + kk) * N2_ + j];

    float cj = 0.f;
    if (tid < HA_) hs[tid] = 0.f;
    __syncthreads();

    for (int a = 0; a < A_; ++a) {
        float acc = kh ? 0.f : z_auth[((size_t)a * G_ + g) * N2_ + j];
#pragma unroll
        for (int kk = 0; kk < 64; ++kk)
            acc += hs[kh * 64 + kk] * rc[kk];
        acc += __shfl_xor(acc, 1);
        if (!kh) gs[j] = acc;
        __syncthreads();
        if (tid < HA_) {
            const float i_ = sigmoidf_(gs[tid]);
            const float f_ = sigmoidf_(gs[tid + 128]);
            const float gg = gs[tid + 256];
            const float o_ = sigmoidf_(gs[tid + 384]);
            cj = f_ * cj + i_ * tanhf_(gg);
            hs[tid] = o_ * tanhf_(cj);
        }
        __syncthreads();
    }
    if (tid < HA_) out[(size_t)g * HA_ + tid] = hs[tid];
}

// ---------------- launch ----------------
extern "C" void kernel_launch(void* const* d_in, const int* in_sizes, int n_in,
                              void* d_out, int out_size, void* d_ws, size_t ws_size,
                              hipStream_t stream) {
    const float* x       = (const float*)d_in[0];
    const float* w_embed = (const float*)d_in[1];
    const float* b_embed = (const float*)d_in[2];
    const float* k_post  = (const float*)d_in[3];
    const float* r_post  = (const float*)d_in[4];
    const float* b_post  = (const float*)d_in[5];
    const float* k_auth  = (const float*)d_in[6];
    const float* r_auth  = (const float*)d_in[7];
    const float* b_auth  = (const float*)d_in[8];
    float* out = (float*)d_out;

    char* wsb = (char*)d_ws;
    _Float16* Zq     = (_Float16*)(wsb);                        // 32 MB (one chunk)
    float*    Bmat   = (float*)(wsb + (32ull << 20));           // 3 MB
    _Float16* Bt16   = (_Float16*)(wsb + (36ull << 20));        // 1.5 MB
    _Float16* Bfrag  = (_Float16*)(wsb + (38ull << 20));        // 512 KB
    float*    biasZp = (float*)(wsb + (38ull << 20) + (512ull << 10));  // 4 KB
    float*    csave  = (float*)(wsb + (39ull << 20));           // 1 MB
    _Float16* hsave  = (_Float16*)(wsb + (40ull << 20));        // 1 MB
    float*    hF32   = (float*)(wsb + (41ull << 20));           // 1 MB
    float*    z_auth = (float*)(wsb + (42ull << 20));           // 2 MB

    // prep
    k_wk    <<<dim3(N1_ / 256, DIN_ / 4), 256, 0, stream>>>(w_embed, k_post, Bmat);
    k_bias_p<<<dim3(N1_ / 256), 256, 0, stream>>>(b_embed, k_post, b_post, biasZp);
    k_t16   <<<dim3(16, 12), 256, 0, stream>>>(Bmat, Bt16);
    k_bfrag <<<dim3(128), 256, 0, stream>>>(r_post, Bfrag);

    // two chunks of 16 timesteps
    for (int ch = 0; ch < 2; ++ch) {
        k_zgemm<<<dim3(512), 512, 0, stream>>>(x, Bt16, biasZp, Zq, ch * TCH);
        k_rec  <<<dim3(64), 1024, 0, stream>>>(Zq, Bfrag, csave, hsave, hF32, ch * TCH);
    }

    // author stage
    k_zauth <<<dim3(N2_ / 256, GA_ / 4), 256, 0, stream>>>(hF32, k_auth, b_auth, z_auth);
    k_author<<<dim3(G_), 1024, 0, stream>>>(z_auth, r_auth, out);
}